// Round 2
// baseline (1671.312 us; speedup 1.0000x reference)
//
#include <hip/hip_runtime.h>
#include <math.h>

constexpr int cB = 128, cN = 512, cF = 128, cOUT = 128;
constexpr float TINYF = 1.401298464324817e-45f;  // np.spacing(0)

// XOR swizzle at float4 granularity: spreads strided-row b128 accesses across banks
__device__ __forceinline__ int sw64(int row, int k) {
  return row * 64 + (k ^ ((row & 7) << 2));
}
__device__ __forceinline__ int sw32(int row, int k) {
  return row * 32 + (k ^ ((row & 7) << 2));
}

// ---------------- Kernel A: xw = x @ M_L ; sq = rowsum(xw^2) ----------------
constexpr int ROWS_A = 16;
__global__ __launch_bounds__(256) void k_xw(
    const float* __restrict__ x, const float* __restrict__ M,
    float* __restrict__ xw, float* __restrict__ sq) {
  __shared__ float Ms[64 * 128];        // K-chunk of M_L, [k][col]
  __shared__ float xs[ROWS_A * 128];    // staged x rows
  __shared__ float red[ROWS_A][2];
  int t = threadIdx.x;
  long base = (long)blockIdx.x * ROWS_A * cF;
  for (int i = t; i < ROWS_A * cF; i += 256) xs[i] = x[base + i];
  int col = t & 127, rg = t >> 7;
  float acc[ROWS_A / 2];
#pragma unroll
  for (int r = 0; r < ROWS_A / 2; ++r) acc[r] = 0.f;
  for (int c = 0; c < 2; ++c) {
    __syncthreads();
    for (int i = t; i < 64 * 128; i += 256) Ms[i] = M[c * 64 * cF + i];
    __syncthreads();
#pragma unroll
    for (int r = 0; r < ROWS_A / 2; ++r) {
      int row = rg + 2 * r;
      float s = acc[r];
#pragma unroll 16
      for (int k = 0; k < 64; ++k) s += xs[row * cF + c * 64 + k] * Ms[k * cF + col];
      acc[r] = s;
    }
  }
#pragma unroll
  for (int r = 0; r < ROWS_A / 2; ++r) {
    int row = rg + 2 * r;
    xw[base + row * cF + col] = acc[r];
    float v = acc[r] * acc[r];
#pragma unroll
    for (int o = 32; o > 0; o >>= 1) v += __shfl_down(v, o);
    if ((t & 63) == 0) red[row][(t >> 6) & 1] = v;
  }
  __syncthreads();
  if (t < ROWS_A) sq[blockIdx.x * ROWS_A + t] = red[t][0] + red[t][1];
}

// ---------------- Kernel B: per-batch Gram + W = exp(-sqrt(d2)) * (1-eye) ----
__global__ __launch_bounds__(256) void k_gram_w(
    const float* __restrict__ xw, const float* __restrict__ sq,
    float* __restrict__ Wout) {
  __shared__ float As[64 * 64], Bs[64 * 64];
  int b = blockIdx.y;
  int i0 = (blockIdx.x >> 3) * 64, j0 = (blockIdx.x & 7) * 64;
  const float* Xb = xw + (long)b * cN * cF;
  int t = threadIdx.x, tx = t & 15, ty = t >> 4;
  int lk4 = (t & 15) * 4, lr = t >> 4;
  float acc[4][4] = {{0.f}};
  for (int c = 0; c < 2; ++c) {
    __syncthreads();
#pragma unroll
    for (int p = 0; p < 4; ++p) {
      int row = lr + p * 16;
      *(float4*)&As[sw64(row, lk4)] = *(const float4*)&Xb[(long)(i0 + row) * cF + c * 64 + lk4];
      *(float4*)&Bs[sw64(row, lk4)] = *(const float4*)&Xb[(long)(j0 + row) * cF + c * 64 + lk4];
    }
    __syncthreads();
#pragma unroll
    for (int k4 = 0; k4 < 64; k4 += 4) {
      float4 af[4], bf[4];
#pragma unroll
      for (int a = 0; a < 4; ++a) af[a] = *(const float4*)&As[sw64(ty * 4 + a, k4)];
#pragma unroll
      for (int q = 0; q < 4; ++q) bf[q] = *(const float4*)&Bs[sw64(tx * 4 + q, k4)];
#pragma unroll
      for (int a = 0; a < 4; ++a)
#pragma unroll
        for (int q = 0; q < 4; ++q)
          acc[a][q] += af[a].x * bf[q].x + af[a].y * bf[q].y + af[a].z * bf[q].z + af[a].w * bf[q].w;
    }
  }
  const float* sqb = sq + b * cN;
  float* Wb = Wout + (long)b * cN * cN;
#pragma unroll
  for (int a = 0; a < 4; ++a) {
    int i = i0 + ty * 4 + a;
    float si = sqb[i];
    float4 wv;
    float* wp = (float*)&wv;
#pragma unroll
    for (int q = 0; q < 4; ++q) {
      int j = j0 + tx * 4 + q;
      float raw = si + sqb[j] - 2.f * acc[a][q];
      wp[q] = (i == j) ? 0.f : expf(-sqrtf(fmaxf(raw, 0.f)));
    }
    *(float4*)&Wb[(long)i * cN + j0 + tx * 4] = wv;
  }
}

// ---------------- Kernel C: dis = 1/sqrt(rowsum(W) + TINY) ------------------
__global__ void k_dis(const float* __restrict__ Wout, float* __restrict__ dis) {
  long row = blockIdx.x;
  const float* wr = Wout + row * cN;
  int t = threadIdx.x;  // 64
  float4 v1 = *(const float4*)&wr[t * 8];
  float4 v2 = *(const float4*)&wr[t * 8 + 4];
  float s = v1.x + v1.y + v1.z + v1.w + v2.x + v2.y + v2.z + v2.w;
#pragma unroll
  for (int o = 32; o > 0; o >>= 1) s += __shfl_down(s, o);
  if (t == 0) dis[row] = 1.f / sqrtf(s + TINYF);
}

// ---------------- Kernel D: ssq[b] += sum_offdiag (dis_i W dis_j)^2 ---------
__global__ void k_ssq(const float* __restrict__ Wout, const float* __restrict__ dis,
                      float* __restrict__ ssq) {
  long row = blockIdx.x;
  int b = (int)(row >> 9), i = (int)(row & 511);
  const float* wr = Wout + row * cN;
  const float* db = dis + ((long)b << 9);
  float di = db[i];
  int t = threadIdx.x;  // 64
  float s = 0.f;
#pragma unroll
  for (int p = 0; p < 2; ++p) {
    int j = t * 8 + p * 4;
    float4 w = *(const float4*)&wr[j];
    float4 dj = *(const float4*)&db[j];
    float e0 = di * w.x * dj.x, e1 = di * w.y * dj.y;
    float e2 = di * w.z * dj.z, e3 = di * w.w * dj.w;
    s += e0 * e0 + e1 * e1 + e2 * e2 + e3 * e3;
  }
#pragma unroll
  for (int o = 32; o > 0; o >>= 1) s += __shfl_down(s, o);
  if (t == 0) atomicAdd(&ssq[b], s);
}

// ---------------- Kernel E: per-batch clip scale ----------------------------
__global__ void k_scale(const float* __restrict__ ssq, float* __restrict__ scal) {
  int b = threadIdx.x;
  if (b < cB) {
    float an = sqrtf((float)cN + ssq[b]) / ((float)cN * (float)cN);
    scal[b] = 1.f / fmaxf(an, 1.f);
  }
}

// ---------------- Kernel F: L = leakyrelu(scale * (eye - dis W dis)) --------
__global__ __launch_bounds__(256) void k_L(
    const float* __restrict__ Wout, const float* __restrict__ dis,
    const float* __restrict__ scal, const float* __restrict__ alpha,
    float* __restrict__ Lout) {
  long tot4 = (long)cB * cN * cN / 4;
  long idx = (long)blockIdx.x * blockDim.x + threadIdx.x;
  long stride = (long)gridDim.x * blockDim.x;
  float al = alpha[0];
  for (long p = idx; p < tot4; p += stride) {
    long e = p * 4;
    int b = (int)(e >> 18);          // N*N = 262144
    int i = (int)((e >> 9) & 511);
    int j = (int)(e & 511);
    float di = dis[((long)b << 9) + i];
    float sc = scal[b];
    float4 w = *(const float4*)&Wout[e];
    float4 dj = *(const float4*)&dis[((long)b << 9) + j];
    const float* wp = (const float*)&w;
    const float* dp = (const float*)&dj;
    float4 o;
    float* op = (float*)&o;
#pragma unroll
    for (int q = 0; q < 4; ++q) {
      float v = (i == j + q) ? 1.f : -(di * wp[q] * dp[q]);
      v *= sc;
      op[q] = (v >= 0.f) ? v : al * v;
    }
    *(float4*)&Lout[e] = o;
  }
}

// ---------------- Kernel G: x1 = (L + lap) @ x  (per batch) -----------------
__global__ __launch_bounds__(256) void k_cheb(
    const float* __restrict__ Lout, const float* __restrict__ lap,
    const float* __restrict__ x, float* __restrict__ x1) {
  __shared__ float As[64 * 64], Bs[64 * 64];
  int b = blockIdx.y;
  int i0 = (blockIdx.x >> 1) * 64, f0 = (blockIdx.x & 1) * 64;
  long lbase = (long)b * cN * cN;
  const float* xb = x + (long)b * cN * cF;
  int t = threadIdx.x, tx = t & 15, ty = t >> 4;
  int lk4 = (t & 15) * 4, lr = t >> 4;
  float acc[4][4] = {{0.f}};
  for (int c = 0; c < 8; ++c) {
    __syncthreads();
#pragma unroll
    for (int p = 0; p < 4; ++p) {
      int row = lr + p * 16;
      long ge = lbase + (long)(i0 + row) * cN + c * 64 + lk4;
      float4 va = *(const float4*)&Lout[ge];
      float4 vl = *(const float4*)&lap[ge];
      va.x += vl.x; va.y += vl.y; va.z += vl.z; va.w += vl.w;
      *(float4*)&As[sw64(row, lk4)] = va;
      *(float4*)&Bs[sw64(row, lk4)] = *(const float4*)&xb[(long)(c * 64 + row) * cF + f0 + lk4];
    }
    __syncthreads();
#pragma unroll
    for (int k4 = 0; k4 < 64; k4 += 4) {
      float av[4][4], bv[4][4];
#pragma unroll
      for (int a = 0; a < 4; ++a) {
        float4 v = *(const float4*)&As[sw64(ty * 4 + a, k4)];
        av[a][0] = v.x; av[a][1] = v.y; av[a][2] = v.z; av[a][3] = v.w;
      }
#pragma unroll
      for (int q = 0; q < 4; ++q) {
        float4 v = *(const float4*)&Bs[sw64(k4 + q, tx * 4)];
        bv[q][0] = v.x; bv[q][1] = v.y; bv[q][2] = v.z; bv[q][3] = v.w;
      }
#pragma unroll
      for (int a = 0; a < 4; ++a)
#pragma unroll
        for (int j = 0; j < 4; ++j)
          acc[a][j] += av[a][0] * bv[0][j] + av[a][1] * bv[1][j] +
                       av[a][2] * bv[2][j] + av[a][3] * bv[3][j];
    }
  }
#pragma unroll
  for (int a = 0; a < 4; ++a) {
    float4 o = {acc[a][0], acc[a][1], acc[a][2], acc[a][3]};
    *(float4*)&x1[(long)b * cN * cF + (long)(i0 + ty * 4 + a) * cF + f0 + tx * 4] = o;
  }
}

// ---------------- Kernel H: out = relu(xk @ weight + bias), IN-PLACE over x1 ----
// Full-width tile: 64 rows x 128 out-cols per block, so each block reads only its
// own rows of x1 (== out region) before writing them. xk interleave (f*K+k) handled
// by strided weight rows: B0=weight[2f], B1=weight[2f+1].
__global__ __launch_bounds__(256) void k_out(
    const float* __restrict__ x, const float* __restrict__ x1,
    const float* __restrict__ wt, const float* __restrict__ bias,
    float* __restrict__ out) {
  __shared__ float A0[64 * 32], A1[64 * 32];     // 8 KB each
  __shared__ float B0s[32 * 128], B1s[32 * 128]; // 16 KB each
  long r0 = (long)blockIdx.x * 64;
  int t = threadIdx.x, tx = t & 31, ty = t >> 5;  // tx: col4 0..31, ty: row 0..7
  float acc[8][4] = {{0.f}};
  for (int c = 0; c < 4; ++c) {
    __syncthreads();
    {
      int lk4 = (t & 7) * 4, lr = t >> 3;  // 32 rows/pass over A
#pragma unroll
      for (int p = 0; p < 2; ++p) {
        int row = lr + p * 32;
        *(float4*)&A0[sw32(row, lk4)] = *(const float4*)&x[(r0 + row) * cF + c * 32 + lk4];
        *(float4*)&A1[sw32(row, lk4)] = *(const float4*)&x1[(r0 + row) * cF + c * 32 + lk4];
      }
      int col4 = (t & 31) * 4, kr = t >> 5;  // 8 k-rows/pass over B
#pragma unroll
      for (int p = 0; p < 4; ++p) {
        int k = kr + p * 8;
        *(float4*)&B0s[k * 128 + col4] = *(const float4*)&wt[(long)((c * 32 + k) * 2) * cOUT + col4];
        *(float4*)&B1s[k * 128 + col4] = *(const float4*)&wt[(long)((c * 32 + k) * 2 + 1) * cOUT + col4];
      }
    }
    __syncthreads();
#pragma unroll
    for (int k = 0; k < 32; ++k) {
      float b0[4], b1[4];
      float4 v = *(const float4*)&B0s[k * 128 + tx * 4];
      b0[0] = v.x; b0[1] = v.y; b0[2] = v.z; b0[3] = v.w;
      float4 u = *(const float4*)&B1s[k * 128 + tx * 4];
      b1[0] = u.x; b1[1] = u.y; b1[2] = u.z; b1[3] = u.w;
#pragma unroll
      for (int a = 0; a < 8; ++a) {
        int row = ty + 8 * a;
        float a0 = A0[sw32(row, k)];  // swizzle bits are >= bit2, scalar index safe
        float a1 = A1[sw32(row, k)];
#pragma unroll
        for (int q = 0; q < 4; ++q) acc[a][q] += a0 * b0[q] + a1 * b1[q];
      }
    }
  }
  __syncthreads();  // all x1 reads complete before in-place out writes
#pragma unroll
  for (int a = 0; a < 8; ++a) {
    int row = ty + 8 * a;
    float4 o;
    float* op = (float*)&o;
#pragma unroll
    for (int q = 0; q < 4; ++q) {
      float v = acc[a][q] + bias[tx * 4 + q];
      op[q] = v > 0.f ? v : 0.f;
    }
    *(float4*)&out[(r0 + row) * cOUT + tx * 4] = o;
  }
}

// ---------------- Host launch ----------------------------------------------
extern "C" void kernel_launch(void* const* d_in, const int* in_sizes, int n_in,
                              void* d_out, int out_size, void* d_ws, size_t ws_size,
                              hipStream_t stream) {
  const float* x = (const float*)d_in[0];
  const float* lap = (const float*)d_in[1];
  const float* M = (const float*)d_in[2];
  const float* alpha = (const float*)d_in[3];
  const float* wt = (const float*)d_in[4];
  const float* bias = (const float*)d_in[5];

  float* out = (float*)d_out;                       // [B,N,OUT]
  float* Lout = out + (long)cB * cN * cOUT;         // [B,N,N]
  float* Wout = Lout + (long)cB * cN * cN;          // [B,N,N]

  // Big scratch lives inside d_out regions that are dead at time of use:
  //   xw -> L slot (L written later, after xw consumed)
  //   x1 -> out slot (k_out reads x1 rows then writes same rows in-place)
  float* xw = Lout;                                 // B*N*F (< B*N*N region)
  float* x1 = out;                                  // B*N*F == B*N*OUT

  // Small scratch in d_ws (~513 KB)
  float* ws = (float*)d_ws;
  float* sq = ws;                                   // B*N
  float* dis = sq + (long)cB * cN;                  // B*N
  float* ssq = dis + (long)cB * cN;                 // B
  float* scal = ssq + cB;                           // B

  k_xw<<<dim3(cB * cN / ROWS_A), 256, 0, stream>>>(x, M, xw, sq);
  k_gram_w<<<dim3(64, cB), 256, 0, stream>>>(xw, sq, Wout);
  k_dis<<<dim3(cB * cN), 64, 0, stream>>>(Wout, dis);
  hipMemsetAsync(ssq, 0, cB * sizeof(float), stream);
  k_ssq<<<dim3(cB * cN), 64, 0, stream>>>(Wout, dis, ssq);
  k_scale<<<1, 128, 0, stream>>>(ssq, scal);
  k_L<<<dim3(2048), 256, 0, stream>>>(Wout, dis, scal, alpha, Lout);
  k_cheb<<<dim3(16, cB), 256, 0, stream>>>(Lout, lap, x, x1);
  k_out<<<dim3(cB * cN / 64), 256, 0, stream>>>(x, x1, wt, bias, out);
}